// Round 6
// baseline (59.005 us; speedup 1.0000x reference)
//
#include <hip/hip_runtime.h>

// BezierGlyph R6: two waves per 8x8 tile, parity-split sample lists.
// 4096 blocks x 128 threads; block = one 8x8 pixel tile, 2 waves.
// Wave w owns samples {2i+w} (parity interleave -> balanced lists for any
// geometry). Anchored logsumexp (exact, see R5):
//   md = A - log2( sum_k exp2(C*(A - d_k)) ) / C,  A = sqrt(min_all bb2),
// A block-uniform via one LDS exchange; partial sums S_w share the anchor so
// S = S_0 + S_1 is exact. Cull: keep sample iff bbox-dist^2 <= T^2,
//   T = min(A + 2*HD, FARCUT) + RADIUS;
// dropped terms each < exp(-256*0.06) ~ 2e-7; saturated pixels (d > FARCUT)
// are 1 within 7.5e-6. Far tile (A > FARCUT): store 1.0, exit (pre-barrier,
// block-uniform -> barrier-safe).

#define SIZE 512
#define RADIUS 0.06f
#define FARCUT 0.1217f          // 0.04 + ln(256)/256 + RADIUS
#define HB 0.00684932f          // 3.5/511    (pixel-center bbox half-extent)
#define HD 0.00968631f          // HB*sqrt(2) (bbox half-diagonal)

__device__ __forceinline__ float clamp01(float x) {
    return fminf(fmaxf(x, 0.0f), 1.0f);
}
__device__ __forceinline__ float wave_min(float v) {
    #pragma unroll
    for (int m = 1; m < 64; m <<= 1) v = fminf(v, __shfl_xor(v, m));
    return v;
}

__global__ __launch_bounds__(128, 8) void bezier_glyph_kernel(
        const float* __restrict__ cp,   // (8,4,2) control points
        float* __restrict__ out)        // (512*512)
{
    __shared__ float2 lists[2][136];
    __shared__ float  aMin[2];
    __shared__ float  redS[128];

    const int tid  = threadIdx.x;
    const int lane = tid & 63;
    const int wid  = tid >> 6;

    const int b        = blockIdx.x;
    const int row_base = (b >> 6) << 3;
    const int col_base = (b & 63) << 3;
    const float inv = 1.0f / 511.0f;
    const float cx  = ((float)col_base + 3.5f) * inv;
    const float cy  = ((float)row_base + 3.5f) * inv;

    // ---- Stage 0: this thread evaluates samples 128r + 2*lane + wid ----
    float sxv[2], syv[2], bb2v[2];
    #pragma unroll
    for (int r = 0; r < 2; ++r) {
        const int k = (r << 7) + (lane << 1) + wid;   // global sample idx
        const float* p = cp + ((k >> 5) << 3);        // stroke base
        const float x0 = clamp01(p[0]), y0 = clamp01(p[1]);
        const float x1 = clamp01(p[2]), y1 = clamp01(p[3]);
        const float x2 = clamp01(p[4]), y2 = clamp01(p[5]);
        const float x3 = clamp01(p[6]), y3 = clamp01(p[7]);
        const float c1x = 3.0f * (x1 - x0);
        const float c2x = 3.0f * (x0 - 2.0f * x1 + x2);
        const float c3x = x3 - x0 + 3.0f * (x1 - x2);
        const float c1y = 3.0f * (y1 - y0);
        const float c2y = 3.0f * (y0 - 2.0f * y1 + y2);
        const float c3y = y3 - y0 + 3.0f * (y1 - y2);
        const float u  = (float)(k & 31) * (1.0f / 31.0f);
        const float sx = fmaf(fmaf(fmaf(c3x, u, c2x), u, c1x), u, x0);
        const float sy = fmaf(fmaf(fmaf(c3y, u, c2y), u, c1y), u, y0);
        sxv[r] = sx; syv[r] = sy;
        const float bx = fmaxf(fabsf(sx - cx) - HB, 0.0f);
        const float by = fmaxf(fabsf(sy - cy) - HB, 0.0f);
        bb2v[r] = fmaf(bx, bx, by * by);
    }

    // ---- block anchor A = sqrt(min over all 256 samples of bb2) ----
    {
        const float wm = wave_min(fminf(bb2v[0], bb2v[1]));
        if (lane == 0) aMin[wid] = wm;
    }
    __syncthreads();
    const float A = __builtin_amdgcn_sqrtf(fminf(aMin[0], aMin[1]));

    const int row = row_base + (lane >> 3);
    const int col = col_base + (lane & 7);

    if (A > FARCUT) {                   // whole tile far: out == 1 (+-7.5e-6)
        if (wid == 0) out[row * SIZE + col] = 1.0f;
        return;
    }

    // ---- per-wave culled list (ballot compaction, no atomics) ----
    const float T  = fminf(A + 2.0f * HD, FARCUT) + RADIUS + 1e-4f;
    const float Ts = T * T;
    const unsigned long long lt = (1ull << lane) - 1ull;
    float2* mylist = lists[wid];
    int n = 0;
    #pragma unroll
    for (int r = 0; r < 2; ++r) {
        const bool keep = (bb2v[r] <= Ts);
        const unsigned long long mk = __ballot(keep);
        if (keep)
            mylist[n + (int)__popcll(mk & lt)] = make_float2(sxv[r], syv[r]);
        n += (int)__popcll(mk);
    }
    if (lane < 4) mylist[n + lane] = make_float2(1e3f, 1e3f);  // pad -> exp2 -> 0
    __syncthreads();

    // ---- anchored pass over this wave's half-list ----
    const float py = (float)row * inv;
    const float px = (float)col * inv;
    const float C  = 369.3299304675766f;   // 256 * log2(e)
    const float nC = -C;
    const float cA = C * A;
    float S = 0.0f;
    const int nr = (n + 3) & ~3;
    for (int k = 0; k < nr; k += 4) {
        const float2 a = mylist[k],     b2 = mylist[k + 1];
        const float2 c = mylist[k + 2], e  = mylist[k + 3];
        float dx, dy;
        dx = px - a.x;  dy = py - a.y;  const float qa = fmaf(dx, dx, dy * dy);
        dx = px - b2.x; dy = py - b2.y; const float qb = fmaf(dx, dx, dy * dy);
        dx = px - c.x;  dy = py - c.y;  const float qc = fmaf(dx, dx, dy * dy);
        dx = px - e.x;  dy = py - e.y;  const float qe = fmaf(dx, dx, dy * dy);
        S += __builtin_amdgcn_exp2f(fmaf(nC, __builtin_amdgcn_sqrtf(qa), cA))
           + __builtin_amdgcn_exp2f(fmaf(nC, __builtin_amdgcn_sqrtf(qb), cA))
           + __builtin_amdgcn_exp2f(fmaf(nC, __builtin_amdgcn_sqrtf(qc), cA))
           + __builtin_amdgcn_exp2f(fmaf(nC, __builtin_amdgcn_sqrtf(qe), cA));
    }
    redS[tid] = S;
    __syncthreads();

    // ---- wave 0 combines and writes ----
    if (wid == 0) {
        const float St = redS[lane] + redS[64 + lane];
        // md = A - log2(St)/C; St==0 -> -inf -> md=+inf -> out=1 (d > FARCUT)
        const float md = A - __builtin_amdgcn_logf(St) * (1.0f / C);
        const float K  = 288.53900817779268f;  // 200 * log2(e)
        out[row * SIZE + col] = __builtin_amdgcn_rcpf(
            1.0f + __builtin_amdgcn_exp2f((0.04f - md) * K));
    }
}

extern "C" void kernel_launch(void* const* d_in, const int* in_sizes, int n_in,
                              void* d_out, int out_size, void* d_ws, size_t ws_size,
                              hipStream_t stream) {
    const float* cp = (const float*)d_in[0];   // control_points (8,4,2)
    float* out = (float*)d_out;                // pixel_grid recomputed in-kernel
    bezier_glyph_kernel<<<dim3(4096), dim3(128), 0, stream>>>(cp, out);
}